// Round 5
// baseline (1799.021 us; speedup 1.0000x reference)
//
#include <hip/hip_runtime.h>

typedef unsigned short ushort_t;
typedef unsigned int uint_t;
typedef __bf16 v8bf __attribute__((ext_vector_type(8)));
typedef float v4f __attribute__((ext_vector_type(4)));

#define DTC 0.1f
#define NB 32768
#define NT 50

union U8 { v8bf v; ushort_t s[8]; };

__device__ __forceinline__ ushort_t f2bf(float f) {
  uint_t u = __float_as_uint(f);
  u += 0x7fffu + ((u >> 16) & 1u);   // RNE
  return (ushort_t)(u >> 16);
}
__device__ __forceinline__ float bf2f(ushort_t s) {
  return __uint_as_float(((uint_t)s) << 16);
}
__device__ __forceinline__ float sigm(float x) {
  return __builtin_amdgcn_rcpf(1.f + __expf(-x));
}
__device__ __forceinline__ float tanhf_(float x) {
  return 1.f - 2.f * __builtin_amdgcn_rcpf(1.f + __expf(2.f * x));
}

// AGPR pin: fragment lives in the accumulator file. MFMA consumes B-operands
// directly from AGPR (ISA §10), so loop uses cost ZERO moves, and the arch
// VGPR budget (128, which the allocator refuses to exceed — r2/r4 evidence)
// is left entirely to the working set. AGPR128+VGPR128 = 256/wave = 2 w/EU.
__device__ __forceinline__ v8bf opaque_a(v8bf x) {
  union { v8bf v; uint_t u[4]; } t; t.v = x;
  asm volatile("" : "+a"(t.u[0]), "+a"(t.u[1]), "+a"(t.u[2]), "+a"(t.u[3]));
  return t.v;
}

// ROUND THEORY (r4: dur 1017us, VGPR=128 AGAIN, VALUBusy 45%, Mfma 19%):
// Allocator pins arch-VGPRs at 128 in every config; the 116+ "persistent"
// fragment values spill, and reload/remat VALU is the stuck 45% VALUBusy
// (~10.8Kcyc/step vs ~4-5Kcyc legit VALU). Fix: pin ALL weight fragments
// (U 64 + E 16 + W1-3 48 = 128 regs) into AGPRs via "+a" asm — first-class
// AGPR values that MFMA reads in place (not spill slots needing accvgpr_read
// per use). u_lds dropped; LDS back to 64,064B. base_pk/c_st stay VGPR
// (VALU-consumed each step). Also: act phase 16x ds_read_u16 -> 2x b128.
//
// LDS layout (shorts), total 32032 sh = 64064 B:
//  hA  : [64][136] @ 0      (8704)   | pe[64][200]=12800 aliases hA+hB (pre-loop)
//  hB  : [64][136] @ 8704   (8704)
//  xa  : [64][136] @ 17408  (8704)
//  ex_s: [64][40]  @ 26112  (2560)
//  sdf : [2][640]f32 @ 28672 (2560)
//  carr: 256 f32   @ 31232  (512)
//  wa  : 128 f32   @ 31744  (256)
//  nrm : 16 f32    @ 32000  (32)

__global__ __launch_bounds__(512) __attribute__((amdgpu_waves_per_eu(2, 2)))
void fsim_kernel(
    const float* __restrict__ proj, const float* __restrict__ ench,
    const float* __restrict__ idm,  const float* __restrict__ mcs,
    const float* __restrict__ smean,const float* __restrict__ svar,
    const float* __restrict__ Wl,   const float* __restrict__ Ul,
    const float* __restrict__ bl,   const float* __restrict__ W1,
    const float* __restrict__ b1,   const float* __restrict__ W2,
    const float* __restrict__ b2,   const float* __restrict__ W3,
    const float* __restrict__ b3,   const float* __restrict__ Wa,
    const float* __restrict__ ba,   float* __restrict__ out) {
  __shared__ __align__(16) short sh[32032];
  short* pe   = sh;                      // aliases hA+hB, pre-loop only
  short* hA   = sh;
  short* hB   = sh + 8704;
  short* xa_s = sh + 17408;
  short* ex_s = sh + 26112;
  float* sdf  = (float*)(sh + 28672);
  float* carr = (float*)(sh + 31232);
  float* wa_s = (float*)(sh + 31744);
  float* nrm  = (float*)(sh + 32000);

  const int tid  = threadIdx.x;
  const int wg   = blockIdx.x;
  const int w    = tid >> 6;
  const int l    = tid & 63;
  const int quad = l >> 4;
  const int c16  = l & 15;
  const int colz = w * 16 + c16;   // unit / MLP column owned by this lane

  float* out_disp = out;
  float* out_act  = out + (size_t)NB * NT;

  // ---- prefetch addressing hoisted; T14 issue-early / write-late split ----
  const int eA = tid / 10, fA = tid - eA * 10;
  const float* pfpA; int pstA;
  if (fA < 7) { pfpA = idm + (size_t)(wg * 64 + eA) * 550 + ((fA == 6) ? 10 : fA); pstA = 11; }
  else        { pfpA = mcs + (size_t)(wg * 64 + eA) * 150 + (fA - 7);              pstA = 3;  }
  const int iB = tid + 512;                 // only valid/used for tid < 128
  const int eB = iB / 10, fB = iB - eB * 10;
  const float* pfpB; int pstB;
  if (fB < 7) { pfpB = idm + (size_t)(wg * 64 + eB) * 550 + ((fB == 6) ? 10 : fB); pstB = 11; }
  else        { pfpB = mcs + (size_t)(wg * 64 + eB) * 150 + (fB - 7);              pstB = 3;  }
  float pfA = pfpA[0];
  float pfB = (tid < 128) ? pfpB[0] : 0.f;

  // ------------- persistent fragments -> AGPRs (128 regs) -------------
  v8bf Uf[4][4];   // [kc][gate]
#pragma unroll
  for (int kc = 0; kc < 4; ++kc) {
#pragma unroll
    for (int g = 0; g < 4; ++g) {
      U8 u;
#pragma unroll
      for (int j = 0; j < 8; ++j)
        u.s[j] = f2bf(Ul[(kc * 32 + quad * 8 + j) * 512 + g * 128 + colz]);
      Uf[kc][g] = opaque_a(u.v);
    }
  }
  v8bf Ef[4];   // env/mc chunk, hi/lo split: k 0..8 hi, 9..17 lo, 18..26 hi
#pragma unroll
  for (int g = 0; g < 4; ++g) {
    U8 u;
#pragma unroll
    for (int j = 0; j < 8; ++j) {
      int kk = quad * 8 + j;
      ushort_t val = 0;
      if (kk < 27) {
        int jj = kk % 9;
        float wv = Wl[(192 + jj) * 512 + g * 128 + colz];
        ushort_t hi = f2bf(wv);
        val = (kk < 9) ? hi : ((kk < 18) ? f2bf(wv - bf2f(hi)) : hi);
      }
      u.s[j] = val;
    }
    Ef[g] = opaque_a(u.v);
  }
  v8bf W1f[4], W2f[4], W3f[4];
#pragma unroll
  for (int kc = 0; kc < 4; ++kc) {
    U8 a, b, c;
#pragma unroll
    for (int j = 0; j < 8; ++j) {
      int row = kc * 32 + quad * 8 + j;
      a.s[j] = f2bf(W1[row * 128 + colz]);
      b.s[j] = f2bf(W2[row * 128 + colz]);
      c.s[j] = f2bf(W3[row * 128 + colz]);
    }
    W1f[kc] = opaque_a(a.v); W2f[kc] = opaque_a(b.v); W3f[kc] = opaque_a(c.v);
  }
  float bias1 = b1[colz], bias2 = b2[colz], bias3 = b3[colz];
  float ba_v  = ba[0];

  // ---------------- LDS setup + t=0 prefetch store + [proj|enc] staging ----------------
  for (int i = tid; i < 2560; i += 512) ex_s[i] = 0;  // zero (covers pad k=27..31)
  if (tid < 6) { nrm[tid] = smean[tid]; nrm[6 + tid] = 1.f / sqrtf(svar[tid]); }
  if (tid < 128) wa_s[tid] = Wa[tid];
  sdf[tid] = pfA;                       // buffer 0 = t=0 features
  if (tid < 128) sdf[512 + tid] = pfB;

  for (int i = tid; i < 64 * 192; i += 512) {
    int e = i / 192, j = i - e * 192;
    float v = (j < 64) ? proj[(wg * 64 + e) * 64 + j]
                       : ench[(wg * 64 + e) * 128 + (j - 64)];
    pe[e * 200 + j] = (short)f2bf(v);
  }
  __syncthreads();

  // ------- base_z = b_lstm + [proj|enc] @ W_lstm[0:192], packed bf16 (once) ------
  uint_t base_pk[4][8];
#pragma unroll
  for (int mt = 0; mt < 4; ++mt) {
    v4f accz[4];
#pragma unroll
    for (int g = 0; g < 4; ++g) {
      float bz = bl[g * 128 + colz];
      accz[g] = (v4f){bz, bz, bz, bz};
    }
    for (int kc = 0; kc < 6; ++kc) {
      const v8bf a = *(const v8bf*)(pe + (mt * 16 + c16) * 200 + kc * 32 + quad * 8);
#pragma unroll
      for (int g = 0; g < 4; ++g) {
        U8 bu;
#pragma unroll
        for (int j = 0; j < 8; ++j)
          bu.s[j] = f2bf(Wl[(kc * 32 + quad * 8 + j) * 512 + g * 128 + colz]);
        accz[g] = __builtin_amdgcn_mfma_f32_16x16x32_bf16(a, bu.v, accz[g], 0, 0, 0);
      }
    }
#pragma unroll
    for (int g = 0; g < 4; ++g) {
      base_pk[mt][g * 2 + 0] = (uint_t)f2bf(accz[g][0]) | ((uint_t)f2bf(accz[g][1]) << 16);
      base_pk[mt][g * 2 + 1] = (uint_t)f2bf(accz[g][2]) | ((uint_t)f2bf(accz[g][3]) << 16);
    }
  }
  __syncthreads();  // pe reads done; region reusable as hA/hB

  // zero hA so the h @ U_lstm GEMM is branch-free at t=0 (h0 == 0)
  for (int i = tid; i < 8704; i += 512) hA[i] = 0;

  v4f c_st[4];
#pragma unroll
  for (int mt = 0; mt < 4; ++mt) c_st[mt] = (v4f){0.f, 0.f, 0.f, 0.f};
  // first read of hA is after bar1 below, so the zeroing is synced.

  for (int t = 0; t < NT; ++t) {
    short* rd = (t & 1) ? hB : hA;   // h[t-1]
    short* wr = (t & 1) ? hA : hB;   // h2 destination (dead buffer)

    // ---- issue next-step idm/mcs loads early; LDS-write happens late ----
    if (t + 1 < NT) {
      pfA = pfpA[(size_t)(t + 1) * pstA];
      if (tid < 128) pfB = pfpB[(size_t)(t + 1) * pstB];
    }

    // ------- phase A (distributed): lane (l&7)==0 of wave w owns e = 8w+(l>>3) ----
    if ((l & 7) == 0) {
      const int e  = w * 8 + (l >> 3);
      const int ge = wg * 64 + e;
      const float* sp = sdf + (t & 1) * 640 + e * 10;
      float s0 = sp[0], s1 = sp[1], s2 = sp[2], s3 = sp[3];
      float s4 = sp[4], s5 = sp[5], s10 = sp[6];
      float mc0 = sp[7], mc1 = sp[8], mc2 = sp[9];
      float pa = 0.f, vv = 0.f, xx = 0.f, dd = 0.f;
      if (t != 0) { pa = carr[192 + e]; vv = carr[e]; xx = carr[64 + e]; dd = carr[128 + e]; }
      float new_v = (t == 0) ? s0 : vv + pa * DTC;
      float delta = new_v * DTC + 0.5f * pa * DTC * DTC;
      float new_x = (t == 0) ? s3 : xx + delta;
      float new_d = (t == 0) ? 0.f : dd + delta;
      float env[9];
      env[0] = new_v;
      env[1] = s1;
      env[2] = new_v - s1;
      env[3] = s4 - new_x;
      env[4] = (new_v - s2) * s10;
      env[5] = (s5 - new_x) * s10 + (1.f - s10) * 100.f;
#pragma unroll
      for (int j = 0; j < 6; ++j) env[j] = (env[j] - nrm[j]) * nrm[6 + j];
      env[6] = mc0; env[7] = mc1; env[8] = mc2;
#pragma unroll
      for (int j = 0; j < 9; ++j) {
        ushort_t hi = f2bf(env[j]);
        ushort_t lo = f2bf(env[j] - bf2f(hi));
        ex_s[e * 40 + j]      = (short)hi;
        ex_s[e * 40 + 9 + j]  = (short)hi;
        ex_s[e * 40 + 18 + j] = (short)lo;
      }
      carr[e] = new_v; carr[64 + e] = new_x; carr[128 + e] = new_d;
      out_disp[(size_t)ge * NT + t] = new_d;
    }
    __syncthreads();  // bar1: ex_s + h ping ready

    // ------- GEMM1 (z) + gates, mt-pairs; U/E fragments from AGPR -------
#pragma unroll
    for (int half = 0; half < 2; ++half) {
      v4f acc[2][4];
#pragma unroll
      for (int m2 = 0; m2 < 2; ++m2) {
        int mt = half * 2 + m2;
#pragma unroll
        for (int g = 0; g < 4; ++g) {
          uint_t w0 = base_pk[mt][g * 2 + 0], w1 = base_pk[mt][g * 2 + 1];
          acc[m2][g][0] = __uint_as_float(w0 << 16);
          acc[m2][g][1] = __uint_as_float(w0 & 0xffff0000u);
          acc[m2][g][2] = __uint_as_float(w1 << 16);
          acc[m2][g][3] = __uint_as_float(w1 & 0xffff0000u);
        }
      }
      {  // env/mc hi-lo chunk
        const v8bf ax0 = *(const v8bf*)(ex_s + ((half * 2 + 0) * 16 + c16) * 40 + quad * 8);
        const v8bf ax1 = *(const v8bf*)(ex_s + ((half * 2 + 1) * 16 + c16) * 40 + quad * 8);
#pragma unroll
        for (int g = 0; g < 4; ++g) {
          acc[0][g] = __builtin_amdgcn_mfma_f32_16x16x32_bf16(ax0, Ef[g], acc[0][g], 0, 0, 0);
          acc[1][g] = __builtin_amdgcn_mfma_f32_16x16x32_bf16(ax1, Ef[g], acc[1][g], 0, 0, 0);
        }
      }
#pragma unroll
      for (int kc = 0; kc < 4; ++kc) {   // h @ U_lstm
        const v8bf a0 = *(const v8bf*)(rd + ((half * 2 + 0) * 16 + c16) * 136 + kc * 32 + quad * 8);
        const v8bf a1 = *(const v8bf*)(rd + ((half * 2 + 1) * 16 + c16) * 136 + kc * 32 + quad * 8);
#pragma unroll
        for (int g = 0; g < 4; ++g) {
          acc[0][g] = __builtin_amdgcn_mfma_f32_16x16x32_bf16(a0, Uf[kc][g], acc[0][g], 0, 0, 0);
          acc[1][g] = __builtin_amdgcn_mfma_f32_16x16x32_bf16(a1, Uf[kc][g], acc[1][g], 0, 0, 0);
        }
      }
#pragma unroll
      for (int m2 = 0; m2 < 2; ++m2) {
        int mt = half * 2 + m2;
        v4f cc = c_st[mt], h2;
#pragma unroll
        for (int r = 0; r < 4; ++r) {
          float ig = sigm(acc[m2][0][r]);
          float fg = sigm(acc[m2][1][r]);
          float gg = tanhf_(acc[m2][2][r]);
          float og = sigm(acc[m2][3][r]);
          float c2 = fg * cc[r] + ig * gg;
          cc[r] = c2;
          h2[r] = og * tanhf_(c2);
        }
        c_st[mt] = cc;
#pragma unroll
        for (int r = 0; r < 4; ++r)      // write h2 into dead buffer (no hazard)
          wr[(mt * 16 + quad * 4 + r) * 136 + colz] = (short)f2bf(h2[r]);
      }
    }
    __syncthreads();  // bar3: h2 visible in wr

    // ------- MLP: 3 x (128x128) with lrelu; weights from AGPR -------
    auto mlp_layer = [&](const short* S, const v8bf* Wf, float bias, short* D) {
      v4f xs[4];
#pragma unroll
      for (int mt = 0; mt < 4; ++mt) {
        v4f acc = (v4f){bias, bias, bias, bias};
#pragma unroll
        for (int kc = 0; kc < 4; ++kc) {
          const v8bf a = *(const v8bf*)(S + (mt * 16 + c16) * 136 + kc * 32 + quad * 8);
          acc = __builtin_amdgcn_mfma_f32_16x16x32_bf16(a, Wf[kc], acc, 0, 0, 0);
        }
#pragma unroll
        for (int r = 0; r < 4; ++r) { float v = acc[r]; acc[r] = (v > 0.f) ? v : 0.3f * v; }
        xs[mt] = acc;
      }
#pragma unroll
      for (int mt = 0; mt < 4; ++mt)
#pragma unroll
        for (int r = 0; r < 4; ++r)
          D[(mt * 16 + quad * 4 + r) * 136 + colz] = (short)f2bf(xs[mt][r]);
    };
    mlp_layer(wr,   W1f, bias1, xa_s);   // x1 = f(h2 @ W1)
    __syncthreads();  // bar4
    mlp_layer(xa_s, W2f, bias2, rd);     // x2 -> rd (dead: old h fully consumed)
    __syncthreads();  // bar5
    mlp_layer(rd,   W3f, bias3, xa_s);   // x3 -> xa (x1 dead)
    // ---- write prefetched t+1 features (other sdf buffer; synced by bar6) ----
    if (t + 1 < NT) {
      sdf[((t + 1) & 1) * 640 + tid] = pfA;
      if (tid < 128) sdf[((t + 1) & 1) * 640 + 512 + tid] = pfB;
    }
    __syncthreads();  // bar6: x3 + sdf ready

    // ------- act = x3 @ Wa + ba; in-wave reduce, b128 reads -------
    {
      const int r = w * 8 + (l >> 3);    // row owned by this 8-lane group
      const int p = l & 7;
      U8 va, vb;
      va.v = *(const v8bf*)(xa_s + r * 136 + p * 16);
      vb.v = *(const v8bf*)(xa_s + r * 136 + p * 16 + 8);
      float s = 0.f;
#pragma unroll
      for (int i = 0; i < 8; ++i) s += bf2f(va.s[i]) * wa_s[p * 16 + i];
#pragma unroll
      for (int i = 0; i < 8; ++i) s += bf2f(vb.s[i]) * wa_s[p * 16 + 8 + i];
      s += __shfl_xor(s, 1);
      s += __shfl_xor(s, 2);
      s += __shfl_xor(s, 4);
      if ((l & 7) == 0) {
        float a = s + ba_v;
        carr[192 + r] = a;  // read next step by THIS SAME thread (phase A)
        out_act[(size_t)(wg * 64 + r) * NT + t] = a;
      }
    }
  }
}

extern "C" void kernel_launch(void* const* d_in, const int* in_sizes, int n_in,
                              void* d_out, int out_size, void* d_ws, size_t ws_size,
                              hipStream_t stream) {
  (void)in_sizes; (void)n_in; (void)out_size; (void)d_ws; (void)ws_size;
  fsim_kernel<<<dim3(512), dim3(512), 0, stream>>>(
      (const float*)d_in[0],  (const float*)d_in[1],  (const float*)d_in[2],
      (const float*)d_in[3],  (const float*)d_in[4],  (const float*)d_in[5],
      (const float*)d_in[6],  (const float*)d_in[7],  (const float*)d_in[8],
      (const float*)d_in[9],  (const float*)d_in[10], (const float*)d_in[11],
      (const float*)d_in[12], (const float*)d_in[13], (const float*)d_in[14],
      (const float*)d_in[15], (const float*)d_in[16], (float*)d_out);
}

// Round 7
// 1746.073 us; speedup vs baseline: 1.0303x; 1.0303x over previous
//
#include <hip/hip_runtime.h>

typedef unsigned short ushort_t;
typedef unsigned int uint_t;
typedef __bf16 v8bf __attribute__((ext_vector_type(8)));
typedef float v4f __attribute__((ext_vector_type(4)));

#define DTC 0.1f
#define NB 32768
#define NT 50

union U8 { v8bf v; ushort_t s[8]; };

__device__ __forceinline__ ushort_t f2bf(float f) {
  uint_t u = __float_as_uint(f);
  u += 0x7fffu + ((u >> 16) & 1u);   // RNE
  return (ushort_t)(u >> 16);
}
__device__ __forceinline__ float bf2f(ushort_t s) {
  return __uint_as_float(((uint_t)s) << 16);
}
__device__ __forceinline__ float sigm(float x) {
  return __builtin_amdgcn_rcpf(1.f + __expf(-x));
}
__device__ __forceinline__ float tanhf_(float x) {
  return 1.f - 2.f * __builtin_amdgcn_rcpf(1.f + __expf(2.f * x));
}

// ROUND THEORY (resubmit — GPU timeout, never benched):
// r2/r4/r5: register residency for ~128 weight values FAILS in every form
// (remat VALU 45% / scratch spill 3.3GB FETCH). r3: d_ws is UNCACHED. But
// d_in global loads L2-cache fine (70-77MB FETCH all healthy rounds).
// FIX: pre-pack bf16 fragments into a module __device__ array (NORMAL cached
// VRAM, not d_ws) via a pack kernel; main kernel loads each fragment per use:
// ONE global_load_dwordx4 (L2 hit) instead of 30 VALU. No residency needed.
// Opaque per-iteration zero offset stops the compiler from re-hoisting the
// invariant loads into loop-persistent regs. No pinned weights -> 128 VGPR
// fits, LDS 64,064B -> 2 WGs/CU (cross-WG phase overlap), waves_per_eu(4).
//
// g_frags layout (ushort): [group 0..7][tid 0..511][f 0..3][8]
//   thread byte offset = group*32768 + tid*64 + f*16  (64B/thread/group)
//   groups 0..3: U_lstm kc=group, f=gate
//   group  4   : env/mc chunk, f=gate (hi/lo split rows)
//   groups 5..7: W1/W2/W3, f=kc
//
// LDS layout (shorts), total 32032 sh = 64064 B (2 WG/CU = 128,128B <= 160K):
//  hA  : [64][136] @ 0      (8704)   | pe[64][200]=12800 aliases hA+hB (pre-loop)
//  hB  : [64][136] @ 8704   (8704)
//  xa  : [64][136] @ 17408  (8704)
//  ex_s: [64][40]  @ 26112  (2560)
//  sdf : [2][640]f32 @ 28672 (2560)
//  carr: 256 f32   @ 31232  (512)
//  wa  : 128 f32   @ 31744  (256)
//  nrm : 16 f32    @ 32000  (32)

__device__ ushort_t g_frags[8 * 512 * 4 * 8];   // 256 KB, L2-cached VRAM

__global__ __launch_bounds__(512)
void pack_kernel(const float* __restrict__ Ul, const float* __restrict__ Wl,
                 const float* __restrict__ W1, const float* __restrict__ W2,
                 const float* __restrict__ W3) {
  const int tid  = threadIdx.x;
  const int b    = blockIdx.x;          // group 0..7
  const int l    = tid & 63;
  const int wv   = tid >> 6;
  const int quad = l >> 4;
  const int c16  = l & 15;
  const int colz = wv * 16 + c16;
  ushort_t* dst = g_frags + ((size_t)b * 512 + tid) * 32;
  if (b < 4) {                          // U_lstm, kc = b, f = gate
#pragma unroll
    for (int f = 0; f < 4; ++f) {
      U8 u;
#pragma unroll
      for (int j = 0; j < 8; ++j)
        u.s[j] = f2bf(Ul[(b * 32 + quad * 8 + j) * 512 + f * 128 + colz]);
      *(v8bf*)(dst + f * 8) = u.v;
    }
  } else if (b == 4) {                  // env/mc chunk, hi/lo split
#pragma unroll
    for (int f = 0; f < 4; ++f) {
      U8 u;
#pragma unroll
      for (int j = 0; j < 8; ++j) {
        int kk = quad * 8 + j;
        ushort_t val = 0;
        if (kk < 27) {
          int jj = kk % 9;
          float wvv = Wl[(192 + jj) * 512 + f * 128 + colz];
          ushort_t hi = f2bf(wvv);
          val = (kk < 9) ? hi : ((kk < 18) ? f2bf(wvv - bf2f(hi)) : hi);
        }
        u.s[j] = val;
      }
      *(v8bf*)(dst + f * 8) = u.v;
    }
  } else {                              // W1/W2/W3, f = kc
    const float* Wp = (b == 5) ? W1 : ((b == 6) ? W2 : W3);
#pragma unroll
    for (int f = 0; f < 4; ++f) {
      U8 u;
#pragma unroll
      for (int j = 0; j < 8; ++j)
        u.s[j] = f2bf(Wp[(f * 32 + quad * 8 + j) * 128 + colz]);
      *(v8bf*)(dst + f * 8) = u.v;
    }
  }
}

__global__ __launch_bounds__(512) __attribute__((amdgpu_waves_per_eu(4)))
void fsim_kernel(
    const float* __restrict__ proj, const float* __restrict__ ench,
    const float* __restrict__ idm,  const float* __restrict__ mcs,
    const float* __restrict__ smean,const float* __restrict__ svar,
    const float* __restrict__ Wl,   const float* __restrict__ bl,
    const float* __restrict__ b1,   const float* __restrict__ b2,
    const float* __restrict__ b3,   const float* __restrict__ Wa,
    const float* __restrict__ ba,   float* __restrict__ out) {
  __shared__ __align__(16) short sh[32032];
  short* pe   = sh;                      // aliases hA+hB, pre-loop only
  short* hA   = sh;
  short* hB   = sh + 8704;
  short* xa_s = sh + 17408;
  short* ex_s = sh + 26112;
  float* sdf  = (float*)(sh + 28672);
  float* carr = (float*)(sh + 31232);
  float* wa_s = (float*)(sh + 31744);
  float* nrm  = (float*)(sh + 32000);

  const int tid  = threadIdx.x;
  const int wg   = blockIdx.x;
  const int w    = tid >> 6;
  const int l    = tid & 63;
  const int quad = l >> 4;
  const int c16  = l & 15;
  const int colz = w * 16 + c16;   // unit / MLP column owned by this lane

  float* out_disp = out;
  float* out_act  = out + (size_t)NB * NT;
  const ushort_t* fbase = g_frags + (size_t)tid * 32;   // +group*16384 +f*8 (ushorts)

  // ---- prefetch addressing hoisted; T14 issue-early / write-late split ----
  const int eA = tid / 10, fA = tid - eA * 10;
  const float* pfpA; int pstA;
  if (fA < 7) { pfpA = idm + (size_t)(wg * 64 + eA) * 550 + ((fA == 6) ? 10 : fA); pstA = 11; }
  else        { pfpA = mcs + (size_t)(wg * 64 + eA) * 150 + (fA - 7);              pstA = 3;  }
  const int iB = tid + 512;                 // only valid/used for tid < 128
  const int eB = iB / 10, fB = iB - eB * 10;
  const float* pfpB; int pstB;
  if (fB < 7) { pfpB = idm + (size_t)(wg * 64 + eB) * 550 + ((fB == 6) ? 10 : fB); pstB = 11; }
  else        { pfpB = mcs + (size_t)(wg * 64 + eB) * 150 + (fB - 7);              pstB = 3;  }
  float pfA = pfpA[0];
  float pfB = (tid < 128) ? pfpB[0] : 0.f;

  float bias1 = b1[colz], bias2 = b2[colz], bias3 = b3[colz];
  float ba_v  = ba[0];

  // ---------------- LDS setup + t=0 prefetch store + [proj|enc] staging ----------------
  for (int i = tid; i < 2560; i += 512) ex_s[i] = 0;  // zero (covers pad k=27..31)
  if (tid < 6) { nrm[tid] = smean[tid]; nrm[6 + tid] = 1.f / sqrtf(svar[tid]); }
  if (tid < 128) wa_s[tid] = Wa[tid];
  sdf[tid] = pfA;                       // buffer 0 = t=0 features
  if (tid < 128) sdf[512 + tid] = pfB;

  for (int i = tid; i < 64 * 192; i += 512) {
    int e = i / 192, j = i - e * 192;
    float v = (j < 64) ? proj[(wg * 64 + e) * 64 + j]
                       : ench[(wg * 64 + e) * 128 + (j - 64)];
    pe[e * 200 + j] = (short)f2bf(v);
  }
  __syncthreads();

  // ------- base_z = b_lstm + [proj|enc] @ W_lstm[0:192], packed bf16 (once) ------
  uint_t base_pk[4][8];
#pragma unroll
  for (int mt = 0; mt < 4; ++mt) {
    v4f accz[4];
#pragma unroll
    for (int g = 0; g < 4; ++g) {
      float bz = bl[g * 128 + colz];
      accz[g] = (v4f){bz, bz, bz, bz};
    }
    for (int kc = 0; kc < 6; ++kc) {
      const v8bf a = *(const v8bf*)(pe + (mt * 16 + c16) * 200 + kc * 32 + quad * 8);
#pragma unroll
      for (int g = 0; g < 4; ++g) {
        U8 bu;
#pragma unroll
        for (int j = 0; j < 8; ++j)
          bu.s[j] = f2bf(Wl[(kc * 32 + quad * 8 + j) * 512 + g * 128 + colz]);
        accz[g] = __builtin_amdgcn_mfma_f32_16x16x32_bf16(a, bu.v, accz[g], 0, 0, 0);
      }
    }
#pragma unroll
    for (int g = 0; g < 4; ++g) {
      base_pk[mt][g * 2 + 0] = (uint_t)f2bf(accz[g][0]) | ((uint_t)f2bf(accz[g][1]) << 16);
      base_pk[mt][g * 2 + 1] = (uint_t)f2bf(accz[g][2]) | ((uint_t)f2bf(accz[g][3]) << 16);
    }
  }
  __syncthreads();  // pe reads done; region reusable as hA/hB

  // zero hA so the h @ U_lstm GEMM is branch-free at t=0 (h0 == 0)
  for (int i = tid; i < 8704; i += 512) hA[i] = 0;

  v4f c_st[4];
#pragma unroll
  for (int mt = 0; mt < 4; ++mt) c_st[mt] = (v4f){0.f, 0.f, 0.f, 0.f};
  // first read of hA is after bar1 below, so the zeroing is synced.

  for (int t = 0; t < NT; ++t) {
    short* rd = (t & 1) ? hB : hA;   // h[t-1]
    short* wr = (t & 1) ? hA : hB;   // h2 destination (dead buffer)

    // opaque zero: makes frag addresses loop-variant so the compiler cannot
    // hoist the (invariant) fragment loads into loop-persistent registers.
    int zo = 0;
    asm volatile("" : "+v"(zo));
    const ushort_t* fb = fbase + zo;

    // ---- issue next-step idm/mcs loads early; LDS-write happens late ----
    if (t + 1 < NT) {
      pfA = pfpA[(size_t)(t + 1) * pstA];
      if (tid < 128) pfB = pfpB[(size_t)(t + 1) * pstB];
    }

    // ------- phase A (distributed): lane (l&7)==0 of wave w owns e = 8w+(l>>3) ----
    if ((l & 7) == 0) {
      const int e  = w * 8 + (l >> 3);
      const int ge = wg * 64 + e;
      const float* sp = sdf + (t & 1) * 640 + e * 10;
      float s0 = sp[0], s1 = sp[1], s2 = sp[2], s3 = sp[3];
      float s4 = sp[4], s5 = sp[5], s10 = sp[6];
      float mc0 = sp[7], mc1 = sp[8], mc2 = sp[9];
      float pa = 0.f, vv = 0.f, xx = 0.f, dd = 0.f;
      if (t != 0) { pa = carr[192 + e]; vv = carr[e]; xx = carr[64 + e]; dd = carr[128 + e]; }
      float new_v = (t == 0) ? s0 : vv + pa * DTC;
      float delta = new_v * DTC + 0.5f * pa * DTC * DTC;
      float new_x = (t == 0) ? s3 : xx + delta;
      float new_d = (t == 0) ? 0.f : dd + delta;
      float env[9];
      env[0] = new_v;
      env[1] = s1;
      env[2] = new_v - s1;
      env[3] = s4 - new_x;
      env[4] = (new_v - s2) * s10;
      env[5] = (s5 - new_x) * s10 + (1.f - s10) * 100.f;
#pragma unroll
      for (int j = 0; j < 6; ++j) env[j] = (env[j] - nrm[j]) * nrm[6 + j];
      env[6] = mc0; env[7] = mc1; env[8] = mc2;
#pragma unroll
      for (int j = 0; j < 9; ++j) {
        ushort_t hi = f2bf(env[j]);
        ushort_t lo = f2bf(env[j] - bf2f(hi));
        ex_s[e * 40 + j]      = (short)hi;
        ex_s[e * 40 + 9 + j]  = (short)hi;
        ex_s[e * 40 + 18 + j] = (short)lo;
      }
      carr[e] = new_v; carr[64 + e] = new_x; carr[128 + e] = new_d;
      out_disp[(size_t)ge * NT + t] = new_d;
    }
    __syncthreads();  // bar1: ex_s + h ping ready

    // ------- GEMM1 (z) + gates, mt-pairs; fragments streamed from L2 -------
#pragma unroll
    for (int half = 0; half < 2; ++half) {
      v4f acc[2][4];
#pragma unroll
      for (int m2 = 0; m2 < 2; ++m2) {
        int mt = half * 2 + m2;
#pragma unroll
        for (int g = 0; g < 4; ++g) {
          uint_t w0 = base_pk[mt][g * 2 + 0], w1 = base_pk[mt][g * 2 + 1];
          acc[m2][g][0] = __uint_as_float(w0 << 16);
          acc[m2][g][1] = __uint_as_float(w0 & 0xffff0000u);
          acc[m2][g][2] = __uint_as_float(w1 << 16);
          acc[m2][g][3] = __uint_as_float(w1 & 0xffff0000u);
        }
      }
      {  // env/mc hi-lo chunk (group 4)
        const v8bf* Ep = (const v8bf*)(fb + 4 * 16384);
        const v8bf ax0 = *(const v8bf*)(ex_s + ((half * 2 + 0) * 16 + c16) * 40 + quad * 8);
        const v8bf ax1 = *(const v8bf*)(ex_s + ((half * 2 + 1) * 16 + c16) * 40 + quad * 8);
#pragma unroll
      for (int g = 0; g < 4; ++g) {
          const v8bf ef = Ep[g];
          acc[0][g] = __builtin_amdgcn_mfma_f32_16x16x32_bf16(ax0, ef, acc[0][g], 0, 0, 0);
          acc[1][g] = __builtin_amdgcn_mfma_f32_16x16x32_bf16(ax1, ef, acc[1][g], 0, 0, 0);
        }
      }
#pragma unroll
      for (int kc = 0; kc < 4; ++kc) {   // h @ U_lstm (groups 0..3)
        const v8bf* Up = (const v8bf*)(fb + kc * 16384);
        const v8bf a0 = *(const v8bf*)(rd + ((half * 2 + 0) * 16 + c16) * 136 + kc * 32 + quad * 8);
        const v8bf a1 = *(const v8bf*)(rd + ((half * 2 + 1) * 16 + c16) * 136 + kc * 32 + quad * 8);
#pragma unroll
        for (int g = 0; g < 4; ++g) {
          const v8bf uf = Up[g];
          acc[0][g] = __builtin_amdgcn_mfma_f32_16x16x32_bf16(a0, uf, acc[0][g], 0, 0, 0);
          acc[1][g] = __builtin_amdgcn_mfma_f32_16x16x32_bf16(a1, uf, acc[1][g], 0, 0, 0);
        }
      }
#pragma unroll
      for (int m2 = 0; m2 < 2; ++m2) {
        int mt = half * 2 + m2;
        v4f cc = c_st[mt], h2;
#pragma unroll
        for (int r = 0; r < 4; ++r) {
          float ig = sigm(acc[m2][0][r]);
          float fg = sigm(acc[m2][1][r]);
          float gg = tanhf_(acc[m2][2][r]);
          float og = sigm(acc[m2][3][r]);
          float c2 = fg * cc[r] + ig * gg;
          cc[r] = c2;
          h2[r] = og * tanhf_(c2);
        }
        c_st[mt] = cc;
#pragma unroll
        for (int r = 0; r < 4; ++r)      // write h2 into dead buffer (no hazard)
          wr[(mt * 16 + quad * 4 + r) * 136 + colz] = (short)f2bf(h2[r]);
      }
    }
    __syncthreads();  // bar3: h2 visible in wr

    // ------- MLP: 3 x (128x128) with lrelu; weights streamed from L2 -------
    auto mlp_layer = [&](const short* S, const ushort_t* WG, float bias, short* D) {
      const v8bf* Wp = (const v8bf*)WG;
      v4f xs[4];
#pragma unroll
      for (int mt = 0; mt < 4; ++mt) {
        v4f acc = (v4f){bias, bias, bias, bias};
#pragma unroll
        for (int kc = 0; kc < 4; ++kc) {
          const v8bf a = *(const v8bf*)(S + (mt * 16 + c16) * 136 + kc * 32 + quad * 8);
          acc = __builtin_amdgcn_mfma_f32_16x16x32_bf16(a, Wp[kc], acc, 0, 0, 0);
        }
#pragma unroll
        for (int r = 0; r < 4; ++r) { float v = acc[r]; acc[r] = (v > 0.f) ? v : 0.3f * v; }
        xs[mt] = acc;
      }
#pragma unroll
      for (int mt = 0; mt < 4; ++mt)
#pragma unroll
        for (int r = 0; r < 4; ++r)
          D[(mt * 16 + quad * 4 + r) * 136 + colz] = (short)f2bf(xs[mt][r]);
    };
    mlp_layer(wr,   fb + 5 * 16384, bias1, xa_s);   // x1 = f(h2 @ W1)
    __syncthreads();  // bar4
    mlp_layer(xa_s, fb + 6 * 16384, bias2, rd);     // x2 -> rd (dead)
    __syncthreads();  // bar5
    mlp_layer(rd,   fb + 7 * 16384, bias3, xa_s);   // x3 -> xa (x1 dead)
    // ---- write prefetched t+1 features (other sdf buffer; synced by bar6) ----
    if (t + 1 < NT) {
      sdf[((t + 1) & 1) * 640 + tid] = pfA;
      if (tid < 128) sdf[((t + 1) & 1) * 640 + 512 + tid] = pfB;
    }
    __syncthreads();  // bar6: x3 + sdf ready

    // ------- act = x3 @ Wa + ba; in-wave reduce, b128 reads -------
    {
      const int r = w * 8 + (l >> 3);    // row owned by this 8-lane group
      const int p = l & 7;
      U8 va, vb;
      va.v = *(const v8bf*)(xa_s + r * 136 + p * 16);
      vb.v = *(const v8bf*)(xa_s + r * 136 + p * 16 + 8);
      float s = 0.f;
#pragma unroll
      for (int i = 0; i < 8; ++i) s += bf2f(va.s[i]) * wa_s[p * 16 + i];
#pragma unroll
      for (int i = 0; i < 8; ++i) s += bf2f(vb.s[i]) * wa_s[p * 16 + 8 + i];
      s += __shfl_xor(s, 1);
      s += __shfl_xor(s, 2);
      s += __shfl_xor(s, 4);
      if ((l & 7) == 0) {
        float a = s + ba_v;
        carr[192 + r] = a;  // read next step by THIS SAME thread (phase A)
        out_act[(size_t)(wg * 64 + r) * NT + t] = a;
      }
    }
  }
}

extern "C" void kernel_launch(void* const* d_in, const int* in_sizes, int n_in,
                              void* d_out, int out_size, void* d_ws, size_t ws_size,
                              hipStream_t stream) {
  (void)in_sizes; (void)n_in; (void)out_size; (void)d_ws; (void)ws_size;
  // 1) pack weight fragments into cached device-global memory (256 KB)
  pack_kernel<<<dim3(8), dim3(512), 0, stream>>>(
      (const float*)d_in[7],  (const float*)d_in[6],  (const float*)d_in[9],
      (const float*)d_in[11], (const float*)d_in[13]);
  // 2) main sim kernel streams fragments from L2
  fsim_kernel<<<dim3(512), dim3(512), 0, stream>>>(
      (const float*)d_in[0],  (const float*)d_in[1],  (const float*)d_in[2],
      (const float*)d_in[3],  (const float*)d_in[4],  (const float*)d_in[5],
      (const float*)d_in[6],  (const float*)d_in[8],  (const float*)d_in[10],
      (const float*)d_in[12], (const float*)d_in[14], (const float*)d_in[15],
      (const float*)d_in[16], (float*)d_out);
}

// Round 8
// 991.870 us; speedup vs baseline: 1.8138x; 1.7604x over previous
//
#include <hip/hip_runtime.h>

typedef unsigned short ushort_t;
typedef unsigned int uint_t;
typedef __bf16 v8bf __attribute__((ext_vector_type(8)));
typedef float v4f __attribute__((ext_vector_type(4)));

#define DTC 0.1f
#define NB 32768
#define NT 50

union U8 { v8bf v; ushort_t s[8]; };

__device__ __forceinline__ ushort_t f2bf(float f) {
  uint_t u = __float_as_uint(f);
  u += 0x7fffu + ((u >> 16) & 1u);   // RNE
  return (ushort_t)(u >> 16);
}
__device__ __forceinline__ float bf2f(ushort_t s) {
  return __uint_as_float(((uint_t)s) << 16);
}
__device__ __forceinline__ float sigm(float x) {
  return __builtin_amdgcn_rcpf(1.f + __expf(-x));
}
__device__ __forceinline__ float tanhf_(float x) {
  return 1.f - 2.f * __builtin_amdgcn_rcpf(1.f + __expf(2.f * x));
}

// ROUND THEORY (r7: dur 1746us, VGPR=64!, WRITE 282MB, FETCH 2.33GB,
// VALUBusy 25%): fragment streaming DID kill remat-VALU (44->25%), but
// waves_per_eu(4) forced a 128-total reg budget -> allocator kept 64 arch
// VGPRs and scratch-spilled the working set (282MB spill-writes + ~2GB
// spill-reads). The L2-streaming idea was contaminated by the occupancy
// experiment. Also: tid*64B layout gave 25% cache-line efficiency.
// THIS ROUND, one variable: clean streaming test.
//  - waves_per_eu(2,2): 256 regs/wave, 1 WG/CU (r2's proven no-spill config)
//  - g_frags layout [frag][tid][8]: wave reads 1KB CONTIGUOUS per frag load
//  - each fragment loaded ONCE per step: GEMM1 kc-outer with acc[4][4] live
//    (64 regs; total live ~160 < 256), MLP unchanged (4 loads/layer).
//    32 loads x 16B /thread/step = 6.7GB L2 demand ~ 1.4TB/s/XCD. OK.
// DECISIVE COUNTERS: WRITE ~80MB (else spill persists); FETCH ~100MB (else
// __device__ globals miss L2 and streaming branch is dead); dur ~550-700.
//
// g_frags layout (ushort): [frag 0..31][tid 0..511][8]
//   frag 0..15 : U_lstm (kc*4+g); 16..19: env/mc (g); 20..31: W1/W2/W3 (kc)
//
// LDS layout (shorts), total 32032 sh = 64064 B:
//  hA  : [64][136] @ 0      (8704)   | pe[64][200]=12800 aliases hA+hB (pre-loop)
//  hB  : [64][136] @ 8704   (8704)
//  xa  : [64][136] @ 17408  (8704)
//  ex_s: [64][40]  @ 26112  (2560)
//  sdf : [2][640]f32 @ 28672 (2560)
//  carr: 256 f32   @ 31232  (512)
//  wa  : 128 f32   @ 31744  (256)
//  nrm : 16 f32    @ 32000  (32)

__device__ ushort_t g_frags[32 * 512 * 8];   // 256 KB, L2-cached VRAM

__global__ __launch_bounds__(512)
void pack_kernel(const float* __restrict__ Ul, const float* __restrict__ Wl,
                 const float* __restrict__ W1, const float* __restrict__ W2,
                 const float* __restrict__ W3) {
  const int tid  = threadIdx.x;
  const int b    = blockIdx.x;          // fragment index 0..31
  const int l    = tid & 63;
  const int wv   = tid >> 6;
  const int quad = l >> 4;
  const int c16  = l & 15;
  const int colz = wv * 16 + c16;
  U8 u;
  if (b < 16) {                         // U_lstm: kc = b>>2, g = b&3
    int kc = b >> 2, g = b & 3;
#pragma unroll
    for (int j = 0; j < 8; ++j)
      u.s[j] = f2bf(Ul[(kc * 32 + quad * 8 + j) * 512 + g * 128 + colz]);
  } else if (b < 20) {                  // env/mc chunk, hi/lo split; g = b-16
    int g = b - 16;
#pragma unroll
    for (int j = 0; j < 8; ++j) {
      int kk = quad * 8 + j;
      ushort_t val = 0;
      if (kk < 27) {
        int jj = kk % 9;
        float wvv = Wl[(192 + jj) * 512 + g * 128 + colz];
        ushort_t hi = f2bf(wvv);
        val = (kk < 9) ? hi : ((kk < 18) ? f2bf(wvv - bf2f(hi)) : hi);
      }
      u.s[j] = val;
    }
  } else {                              // W1/W2/W3: m = (b-20)>>2, kc = (b-20)&3
    int m = (b - 20) >> 2, kc = (b - 20) & 3;
    const float* Wp = (m == 0) ? W1 : ((m == 1) ? W2 : W3);
#pragma unroll
    for (int j = 0; j < 8; ++j)
      u.s[j] = f2bf(Wp[(kc * 32 + quad * 8 + j) * 128 + colz]);
  }
  *(v8bf*)(g_frags + ((size_t)b * 512 + tid) * 8) = u.v;
}

__global__ __launch_bounds__(512) __attribute__((amdgpu_waves_per_eu(2, 2)))
void fsim_kernel(
    const float* __restrict__ proj, const float* __restrict__ ench,
    const float* __restrict__ idm,  const float* __restrict__ mcs,
    const float* __restrict__ smean,const float* __restrict__ svar,
    const float* __restrict__ Wl,   const float* __restrict__ bl,
    const float* __restrict__ b1,   const float* __restrict__ b2,
    const float* __restrict__ b3,   const float* __restrict__ Wa,
    const float* __restrict__ ba,   float* __restrict__ out) {
  __shared__ __align__(16) short sh[32032];
  short* pe   = sh;                      // aliases hA+hB, pre-loop only
  short* hA   = sh;
  short* hB   = sh + 8704;
  short* xa_s = sh + 17408;
  short* ex_s = sh + 26112;
  float* sdf  = (float*)(sh + 28672);
  float* carr = (float*)(sh + 31232);
  float* wa_s = (float*)(sh + 31744);
  float* nrm  = (float*)(sh + 32000);

  const int tid  = threadIdx.x;
  const int wg   = blockIdx.x;
  const int w    = tid >> 6;
  const int l    = tid & 63;
  const int quad = l >> 4;
  const int c16  = l & 15;
  const int colz = w * 16 + c16;   // unit / MLP column owned by this lane

  float* out_disp = out;
  float* out_act  = out + (size_t)NB * NT;
  const ushort_t* fbase = g_frags + (size_t)tid * 8;   // + frag*4096 (ushorts)

  // ---- prefetch addressing hoisted; T14 issue-early / write-late split ----
  const int eA = tid / 10, fA = tid - eA * 10;
  const float* pfpA; int pstA;
  if (fA < 7) { pfpA = idm + (size_t)(wg * 64 + eA) * 550 + ((fA == 6) ? 10 : fA); pstA = 11; }
  else        { pfpA = mcs + (size_t)(wg * 64 + eA) * 150 + (fA - 7);              pstA = 3;  }
  const int iB = tid + 512;                 // only valid/used for tid < 128
  const int eB = iB / 10, fB = iB - eB * 10;
  const float* pfpB; int pstB;
  if (fB < 7) { pfpB = idm + (size_t)(wg * 64 + eB) * 550 + ((fB == 6) ? 10 : fB); pstB = 11; }
  else        { pfpB = mcs + (size_t)(wg * 64 + eB) * 150 + (fB - 7);              pstB = 3;  }
  float pfA = pfpA[0];
  float pfB = (tid < 128) ? pfpB[0] : 0.f;

  float bias1 = b1[colz], bias2 = b2[colz], bias3 = b3[colz];
  float ba_v  = ba[0];

  // ---------------- LDS setup + t=0 prefetch store + [proj|enc] staging ----------------
  for (int i = tid; i < 2560; i += 512) ex_s[i] = 0;  // zero (covers pad k=27..31)
  if (tid < 6) { nrm[tid] = smean[tid]; nrm[6 + tid] = 1.f / sqrtf(svar[tid]); }
  if (tid < 128) wa_s[tid] = Wa[tid];
  sdf[tid] = pfA;                       // buffer 0 = t=0 features
  if (tid < 128) sdf[512 + tid] = pfB;

  for (int i = tid; i < 64 * 192; i += 512) {
    int e = i / 192, j = i - e * 192;
    float v = (j < 64) ? proj[(wg * 64 + e) * 64 + j]
                       : ench[(wg * 64 + e) * 128 + (j - 64)];
    pe[e * 200 + j] = (short)f2bf(v);
  }
  __syncthreads();

  // ------- base_z = b_lstm + [proj|enc] @ W_lstm[0:192], packed bf16 (once) ------
  uint_t base_pk[4][8];
#pragma unroll
  for (int mt = 0; mt < 4; ++mt) {
    v4f accz[4];
#pragma unroll
    for (int g = 0; g < 4; ++g) {
      float bz = bl[g * 128 + colz];
      accz[g] = (v4f){bz, bz, bz, bz};
    }
    for (int kc = 0; kc < 6; ++kc) {
      const v8bf a = *(const v8bf*)(pe + (mt * 16 + c16) * 200 + kc * 32 + quad * 8);
#pragma unroll
      for (int g = 0; g < 4; ++g) {
        U8 bu;
#pragma unroll
        for (int j = 0; j < 8; ++j)
          bu.s[j] = f2bf(Wl[(kc * 32 + quad * 8 + j) * 512 + g * 128 + colz]);
        accz[g] = __builtin_amdgcn_mfma_f32_16x16x32_bf16(a, bu.v, accz[g], 0, 0, 0);
      }
    }
#pragma unroll
    for (int g = 0; g < 4; ++g) {
      base_pk[mt][g * 2 + 0] = (uint_t)f2bf(accz[g][0]) | ((uint_t)f2bf(accz[g][1]) << 16);
      base_pk[mt][g * 2 + 1] = (uint_t)f2bf(accz[g][2]) | ((uint_t)f2bf(accz[g][3]) << 16);
    }
  }
  __syncthreads();  // pe reads done; region reusable as hA/hB

  // zero hA so the h @ U_lstm GEMM is branch-free at t=0 (h0 == 0)
  for (int i = tid; i < 8704; i += 512) hA[i] = 0;

  v4f c_st[4];
#pragma unroll
  for (int mt = 0; mt < 4; ++mt) c_st[mt] = (v4f){0.f, 0.f, 0.f, 0.f};
  // first read of hA is after bar1 below, so the zeroing is synced.

  for (int t = 0; t < NT; ++t) {
    short* rd = (t & 1) ? hB : hA;   // h[t-1]
    short* wr = (t & 1) ? hA : hB;   // h2 destination (dead buffer)

    // opaque zero: keeps frag addresses loop-variant so the compiler cannot
    // hoist the (invariant) fragment loads into loop-persistent registers
    // (which would re-trigger the r2/r4/r5 spill pathology).
    int zo = 0;
    asm volatile("" : "+v"(zo));
    const ushort_t* fb = fbase + zo;

    // ---- issue next-step idm/mcs loads early; LDS-write happens late ----
    if (t + 1 < NT) {
      pfA = pfpA[(size_t)(t + 1) * pstA];
      if (tid < 128) pfB = pfpB[(size_t)(t + 1) * pstB];
    }

    // ------- phase A (distributed): lane (l&7)==0 of wave w owns e = 8w+(l>>3) ----
    if ((l & 7) == 0) {
      const int e  = w * 8 + (l >> 3);
      const int ge = wg * 64 + e;
      const float* sp = sdf + (t & 1) * 640 + e * 10;
      float s0 = sp[0], s1 = sp[1], s2 = sp[2], s3 = sp[3];
      float s4 = sp[4], s5 = sp[5], s10 = sp[6];
      float mc0 = sp[7], mc1 = sp[8], mc2 = sp[9];
      float pa = 0.f, vv = 0.f, xx = 0.f, dd = 0.f;
      if (t != 0) { pa = carr[192 + e]; vv = carr[e]; xx = carr[64 + e]; dd = carr[128 + e]; }
      float new_v = (t == 0) ? s0 : vv + pa * DTC;
      float delta = new_v * DTC + 0.5f * pa * DTC * DTC;
      float new_x = (t == 0) ? s3 : xx + delta;
      float new_d = (t == 0) ? 0.f : dd + delta;
      float env[9];
      env[0] = new_v;
      env[1] = s1;
      env[2] = new_v - s1;
      env[3] = s4 - new_x;
      env[4] = (new_v - s2) * s10;
      env[5] = (s5 - new_x) * s10 + (1.f - s10) * 100.f;
#pragma unroll
      for (int j = 0; j < 6; ++j) env[j] = (env[j] - nrm[j]) * nrm[6 + j];
      env[6] = mc0; env[7] = mc1; env[8] = mc2;
#pragma unroll
      for (int j = 0; j < 9; ++j) {
        ushort_t hi = f2bf(env[j]);
        ushort_t lo = f2bf(env[j] - bf2f(hi));
        ex_s[e * 40 + j]      = (short)hi;
        ex_s[e * 40 + 9 + j]  = (short)hi;
        ex_s[e * 40 + 18 + j] = (short)lo;
      }
      carr[e] = new_v; carr[64 + e] = new_x; carr[128 + e] = new_d;
      out_disp[(size_t)ge * NT + t] = new_d;
    }
    __syncthreads();  // bar1: ex_s + h ping ready

    // ------- GEMM1 (z) + gates; kc-outer, all 4 m-tiles live, frag loaded ONCE ----
    {
      v4f acc[4][4];   // [mt][gate] = 64 VGPRs
#pragma unroll
      for (int mt = 0; mt < 4; ++mt)
#pragma unroll
        for (int g = 0; g < 4; ++g) {
          uint_t w0 = base_pk[mt][g * 2 + 0], w1 = base_pk[mt][g * 2 + 1];
          acc[mt][g][0] = __uint_as_float(w0 << 16);
          acc[mt][g][1] = __uint_as_float(w0 & 0xffff0000u);
          acc[mt][g][2] = __uint_as_float(w1 << 16);
          acc[mt][g][3] = __uint_as_float(w1 & 0xffff0000u);
        }
      {  // env/mc hi-lo chunk: frags 16..19, loaded once
        v8bf Ep[4];
#pragma unroll
        for (int g = 0; g < 4; ++g) Ep[g] = *(const v8bf*)(fb + (16 + g) * 4096);
#pragma unroll
        for (int mt = 0; mt < 4; ++mt) {
          const v8bf ax = *(const v8bf*)(ex_s + (mt * 16 + c16) * 40 + quad * 8);
#pragma unroll
          for (int g = 0; g < 4; ++g)
            acc[mt][g] = __builtin_amdgcn_mfma_f32_16x16x32_bf16(ax, Ep[g], acc[mt][g], 0, 0, 0);
        }
      }
#pragma unroll
      for (int kc = 0; kc < 4; ++kc) {   // h @ U_lstm: frags kc*4+g, loaded once
        v8bf Up[4];
#pragma unroll
        for (int g = 0; g < 4; ++g) Up[g] = *(const v8bf*)(fb + (kc * 4 + g) * 4096);
#pragma unroll
        for (int mt = 0; mt < 4; ++mt) {
          const v8bf a = *(const v8bf*)(rd + (mt * 16 + c16) * 136 + kc * 32 + quad * 8);
#pragma unroll
          for (int g = 0; g < 4; ++g)
            acc[mt][g] = __builtin_amdgcn_mfma_f32_16x16x32_bf16(a, Up[g], acc[mt][g], 0, 0, 0);
        }
      }
#pragma unroll
      for (int mt = 0; mt < 4; ++mt) {
        v4f cc = c_st[mt], h2;
#pragma unroll
        for (int r = 0; r < 4; ++r) {
          float ig = sigm(acc[mt][0][r]);
          float fg = sigm(acc[mt][1][r]);
          float gg = tanhf_(acc[mt][2][r]);
          float og = sigm(acc[mt][3][r]);
          float c2 = fg * cc[r] + ig * gg;
          cc[r] = c2;
          h2[r] = og * tanhf_(c2);
        }
        c_st[mt] = cc;
#pragma unroll
        for (int r = 0; r < 4; ++r)      // write h2 into dead buffer (no hazard)
          wr[(mt * 16 + quad * 4 + r) * 136 + colz] = (short)f2bf(h2[r]);
      }
    }
    __syncthreads();  // bar3: h2 visible in wr

    // ------- MLP: 3 x (128x128) with lrelu; weights streamed from L2 -------
    auto mlp_layer = [&](const short* S, int fidx, float bias, short* D) {
      v8bf Wp[4];
#pragma unroll
      for (int kc = 0; kc < 4; ++kc) Wp[kc] = *(const v8bf*)(fb + (fidx + kc) * 4096);
      v4f xs[4];
#pragma unroll
      for (int mt = 0; mt < 4; ++mt) {
        v4f acc = (v4f){bias, bias, bias, bias};
#pragma unroll
        for (int kc = 0; kc < 4; ++kc) {
          const v8bf a = *(const v8bf*)(S + (mt * 16 + c16) * 136 + kc * 32 + quad * 8);
          acc = __builtin_amdgcn_mfma_f32_16x16x32_bf16(a, Wp[kc], acc, 0, 0, 0);
        }
#pragma unroll
        for (int r = 0; r < 4; ++r) { float v = acc[r]; acc[r] = (v > 0.f) ? v : 0.3f * v; }
        xs[mt] = acc;
      }
#pragma unroll
      for (int mt = 0; mt < 4; ++mt)
#pragma unroll
        for (int r = 0; r < 4; ++r)
          D[(mt * 16 + quad * 4 + r) * 136 + colz] = (short)f2bf(xs[mt][r]);
    };
    mlp_layer(wr,   20, bias1, xa_s);   // x1 = f(h2 @ W1)
    __syncthreads();  // bar4
    mlp_layer(xa_s, 24, bias2, rd);     // x2 -> rd (dead: old h fully consumed)
    __syncthreads();  // bar5
    mlp_layer(rd,   28, bias3, xa_s);   // x3 -> xa (x1 dead)
    // ---- write prefetched t+1 features (other sdf buffer; synced by bar6) ----
    if (t + 1 < NT) {
      sdf[((t + 1) & 1) * 640 + tid] = pfA;
      if (tid < 128) sdf[((t + 1) & 1) * 640 + 512 + tid] = pfB;
    }
    __syncthreads();  // bar6: x3 + sdf ready

    // ------- act = x3 @ Wa + ba; in-wave reduce, b128 reads -------
    {
      const int r = w * 8 + (l >> 3);    // row owned by this 8-lane group
      const int p = l & 7;
      U8 va, vb;
      va.v = *(const v8bf*)(xa_s + r * 136 + p * 16);
      vb.v = *(const v8bf*)(xa_s + r * 136 + p * 16 + 8);
      float s = 0.f;
#pragma unroll
      for (int i = 0; i < 8; ++i) s += bf2f(va.s[i]) * wa_s[p * 16 + i];
#pragma unroll
      for (int i = 0; i < 8; ++i) s += bf2f(vb.s[i]) * wa_s[p * 16 + 8 + i];
      s += __shfl_xor(s, 1);
      s += __shfl_xor(s, 2);
      s += __shfl_xor(s, 4);
      if ((l & 7) == 0) {
        float a = s + ba_v;
        carr[192 + r] = a;  // read next step by THIS SAME thread (phase A)
        out_act[(size_t)(wg * 64 + r) * NT + t] = a;
      }
    }
  }
}

extern "C" void kernel_launch(void* const* d_in, const int* in_sizes, int n_in,
                              void* d_out, int out_size, void* d_ws, size_t ws_size,
                              hipStream_t stream) {
  (void)in_sizes; (void)n_in; (void)out_size; (void)d_ws; (void)ws_size;
  // 1) pack weight fragments into cached device-global memory (256 KB)
  pack_kernel<<<dim3(32), dim3(512), 0, stream>>>(
      (const float*)d_in[7],  (const float*)d_in[6],  (const float*)d_in[9],
      (const float*)d_in[11], (const float*)d_in[13]);
  // 2) main sim kernel streams fragments from L2
  fsim_kernel<<<dim3(512), dim3(512), 0, stream>>>(
      (const float*)d_in[0],  (const float*)d_in[1],  (const float*)d_in[2],
      (const float*)d_in[3],  (const float*)d_in[4],  (const float*)d_in[5],
      (const float*)d_in[6],  (const float*)d_in[8],  (const float*)d_in[10],
      (const float*)d_in[12], (const float*)d_in[14], (const float*)d_in[15],
      (const float*)d_in[16], (float*)d_out);
}